// Round 11
// baseline (501.205 us; speedup 1.0000x reference)
//
#include <hip/hip_runtime.h>

typedef __attribute__((ext_vector_type(4))) float f4;
typedef __attribute__((ext_vector_type(4))) float f32x4;
typedef _Float16 half8 __attribute__((ext_vector_type(8)));

#define DEVI static __device__ __forceinline__

DEVI void gload_lds16(const void* g, void* l) {
  __builtin_amdgcn_global_load_lds(
      (const __attribute__((address_space(1))) void*)g,
      (__attribute__((address_space(3))) void*)l, 16, 0, 0);
}

// bijective XCD swizzle (m204)
DEVI int xcd_swz(int id, int n) {
  int q = n >> 3, r = n & 7;
  int x = id & 7, c = id >> 3;
  return (x < r ? x * (q + 1) : r * (q + 1) + (x - r) * q) + c;
}

#define FENCED_BARRIER()                \
  __builtin_amdgcn_sched_barrier(0);    \
  __builtin_amdgcn_s_barrier();         \
  __builtin_amdgcn_sched_barrier(0);

#define SWZ(kgv, rowv) ((((kgv) ^ ((rowv) >> 1)) & 3) * 8)

// ---------------------------------------------------------------------------
// fp32 -> fp16 conversions.
// ---------------------------------------------------------------------------
__global__ __launch_bounds__(256) void cvt_plain(const float* __restrict__ X,
                                                 _Float16* __restrict__ H,
                                                 int n4) {
  int i = blockIdx.x * 256 + threadIdx.x;
  const int stride = gridDim.x * 256;
  typedef _Float16 half4v __attribute__((ext_vector_type(4)));
  for (; i < n4; i += stride) {
    f4 x = ((const f4*)X)[i];
    half4v h;
#pragma unroll
    for (int j = 0; j < 4; ++j) h[j] = (_Float16)x[j];
    ((half4v*)H)[i] = h;
  }
}

__global__ __launch_bounds__(256) void cvt_split(const float* __restrict__ X,
                                                 _Float16* __restrict__ H,
                                                 _Float16* __restrict__ L,
                                                 int n4) {
  int i = blockIdx.x * 256 + threadIdx.x;
  const int stride = gridDim.x * 256;
  typedef _Float16 half4v __attribute__((ext_vector_type(4)));
  for (; i < n4; i += stride) {
    f4 x = ((const f4*)X)[i];
    half4v h, l;
#pragma unroll
    for (int j = 0; j < 4; ++j) {
      h[j] = (_Float16)x[j];
      l[j] = (_Float16)(x[j] - (float)h[j]);
    }
    ((half4v*)H)[i] = h;
    ((half4v*)L)[i] = l;
  }
}

DEVI void acc_zero44(f32x4 (&acc)[4][4]) {
#pragma unroll
  for (int i = 0; i < 4; ++i)
#pragma unroll
    for (int j = 0; j < 4; ++j) acc[i][j] = (f32x4)0.0f;
}
DEVI void acc_zero42(f32x4 (&acc)[4][2]) {
#pragma unroll
  for (int i = 0; i < 4; ++i)
#pragma unroll
    for (int j = 0; j < 2; ++j) acc[i][j] = (f32x4)0.0f;
}

// ---------------------------------------------------------------------------
// proj3: ring-3 counted-vmcnt projection engine (validated round 10).
// Tile 128x128, 512 thr / 8 waves, wave tile 64x32. OUTMODE 0=Q 1=K 2=Vt.
// ---------------------------------------------------------------------------
template <int WSPLIT, int OUTMODE>
__global__ __launch_bounds__(512, 4) void proj3(
    const _Float16* __restrict__ X, const _Float16* __restrict__ Wh,
    const _Float16* __restrict__ Wl, const float* __restrict__ bias,
    _Float16* __restrict__ OutHi, _Float16* __restrict__ OutLo,
    _Float16* __restrict__ VtOut) {
  extern __shared__ _Float16 lds[];
  constexpr int ACH = 128 * 32;
  constexpr int BCH = 128 * 32;
  constexpr int CHUNK = ACH + BCH * (1 + WSPLIT);
  const int id = xcd_swz(blockIdx.x, gridDim.x);
  const int m0 = (id >> 3) * 128, n0 = (id & 7) * 128;
  const _Float16* A0 = X + (size_t)m0 * 1024;
  const _Float16* B0 = Wh + (size_t)n0 * 1024;
  const _Float16* B1 = Wl + (size_t)n0 * 1024;
  const int tid = threadIdx.x;
  const int w = tid >> 6, lane = tid & 63;
  const int wm = w >> 2, wn = w & 3;
  const int r16 = lane & 15, kg = lane >> 4;
  f32x4 acc[4][2];
  acc_zero42(acc);

  auto STAGE = [&](int t, int buf) {
    _Float16* base = lds + buf * CHUNK;
    int row = tid >> 2, c = tid & 3;
    int cs = (c ^ (row >> 1)) & 3;
    size_t src = (size_t)row * 1024 + t * 32 + cs * 8;
    gload_lds16(A0 + src, base + tid * 8);
    gload_lds16(B0 + src, base + ACH + tid * 8);
    if (WSPLIT) gload_lds16(B1 + src, base + ACH + BCH + tid * 8);
  };
  auto COMPUTE = [&](int buf) {
    const _Float16* la = lds + buf * CHUNK;
    const _Float16* lb = la + ACH;
    half8 a[4], b0f[2], b1f[2];
#pragma unroll
    for (int mi = 0; mi < 4; ++mi) {
      int row = wm * 64 + mi * 16 + r16;
      a[mi] = *(const half8*)(la + row * 32 + SWZ(kg, row));
    }
#pragma unroll
    for (int ni = 0; ni < 2; ++ni) {
      int row = wn * 32 + ni * 16 + r16;
      int off = row * 32 + SWZ(kg, row);
      b0f[ni] = *(const half8*)(lb + off);
      if (WSPLIT) b1f[ni] = *(const half8*)(lb + BCH + off);
    }
    __builtin_amdgcn_s_setprio(1);
#pragma unroll
    for (int mi = 0; mi < 4; ++mi)
#pragma unroll
      for (int ni = 0; ni < 2; ++ni) {
        acc[mi][ni] = __builtin_amdgcn_mfma_f32_16x16x32_f16(
            a[mi], b0f[ni], acc[mi][ni], 0, 0, 0);
        if (WSPLIT)
          acc[mi][ni] = __builtin_amdgcn_mfma_f32_16x16x32_f16(
              a[mi], b1f[ni], acc[mi][ni], 0, 0, 0);
      }
    __builtin_amdgcn_s_setprio(0);
  };

  const int NS = 32;
  STAGE(0, 0);
  STAGE(1, 1);
  int tt = 0;
  for (; tt < NS - 1; ++tt) {
    if constexpr (WSPLIT)
      asm volatile("s_waitcnt vmcnt(3)" ::: "memory");
    else
      asm volatile("s_waitcnt vmcnt(2)" ::: "memory");
    FENCED_BARRIER();
    if (tt + 2 < NS) STAGE(tt + 2, (tt + 2) % 3);
    COMPUTE(tt % 3);
  }
  asm volatile("s_waitcnt vmcnt(0)" ::: "memory");
  FENCED_BARRIER();
  COMPUTE(tt % 3);

  float bcol[2];
#pragma unroll
  for (int ni = 0; ni < 2; ++ni) bcol[ni] = bias[n0 + wn * 32 + ni * 16 + r16];

  if (OUTMODE != 2) {
#pragma unroll
    for (int mi = 0; mi < 4; ++mi) {
      int row = m0 + wm * 64 + mi * 16 + kg * 4;
#pragma unroll
      for (int ni = 0; ni < 2; ++ni) {
        int col = n0 + wn * 32 + ni * 16 + r16;
#pragma unroll
        for (int j = 0; j < 4; ++j) {
          float v = acc[mi][ni][j] + bcol[ni];
          _Float16 h = (_Float16)v;
          OutHi[(size_t)(row + j) * 1024 + col] = h;
          if (OUTMODE == 0)
            OutLo[(size_t)(row + j) * 1024 + col] = (_Float16)(v - (float)h);
        }
      }
    }
  } else {
    __syncthreads();  // ring done; reuse LDS as transpose buffer (32 KB)
    _Float16(*T)[128] = (_Float16(*)[128])lds;
#pragma unroll
    for (int mi = 0; mi < 4; ++mi) {
      int ml = wm * 64 + mi * 16 + kg * 4;
#pragma unroll
      for (int ni = 0; ni < 2; ++ni) {
        int nl = wn * 32 + ni * 16 + r16;
#pragma unroll
        for (int j = 0; j < 4; ++j)
          T[nl][ml + j] = (_Float16)(acc[mi][ni][j] + bcol[ni]);
      }
    }
    __syncthreads();
    const int b = m0 >> 11;
    const int s0 = m0 & 2047;
#pragma unroll
    for (int r = 0; r < 4; ++r) {
      int flat = tid + r * 512;
      int n = flat >> 4, c = flat & 15;
      half8 v = *(const half8*)&T[n][c * 8];
      *(half8*)(VtOut + (size_t)b * (1024 * 2048) + (size_t)(n0 + n) * 2048 +
                s0 + c * 8) = v;
    }
  }
}

// ---------------------------------------------------------------------------
// Fused-cvt projection (fallback when ws is small). Validated round 9.
// ---------------------------------------------------------------------------
template <int WSPLIT, int OUTMODE>
__global__ __launch_bounds__(512, 2) void proj_fused(
    const float* __restrict__ X, const _Float16* __restrict__ Wh,
    const _Float16* __restrict__ Wl, const float* __restrict__ bias,
    _Float16* __restrict__ OutHi, _Float16* __restrict__ OutLo,
    _Float16* __restrict__ VtOut) {
  extern __shared__ _Float16 lds[];
  constexpr int ACH = 256 * 32;
  constexpr int BCH = 128 * 32;
  constexpr int CHUNK = ACH + BCH * (1 + WSPLIT);
  const int id = xcd_swz(blockIdx.x, gridDim.x);
  const int m0 = (id >> 3) * 256, n0 = (id & 7) * 128;
  const float* A = X + (size_t)m0 * 1024;
  const _Float16* B0 = Wh + (size_t)n0 * 1024;
  const _Float16* B1 = Wl + (size_t)n0 * 1024;
  const int tid = threadIdx.x;
  const int w = tid >> 6, lane = tid & 63;
  const int wm = w >> 1, wn = w & 1;
  const int r16 = lane & 15, kg = lane >> 4;
  f32x4 acc[4][4];
  acc_zero44(acc);
  f4 ra[4];

  auto ALOAD = [&](int t) {
#pragma unroll
    for (int j = 0; j < 2; ++j) {
      int g = tid + j * 512;
      int row = g >> 2, c = g & 3;
      const float* src = A + (size_t)row * 1024 + t * 32 + c * 8;
      ra[2 * j] = *(const f4*)src;
      ra[2 * j + 1] = *(const f4*)(src + 4);
    }
  };
  auto AWRITE = [&](int buf) {
    _Float16* ab = lds + buf * CHUNK;
#pragma unroll
    for (int j = 0; j < 2; ++j) {
      int g = tid + j * 512;
      int row = g >> 2, c = g & 3;
      half8 h;
#pragma unroll
      for (int e = 0; e < 4; ++e) {
        h[e] = (_Float16)ra[2 * j][e];
        h[e + 4] = (_Float16)ra[2 * j + 1][e];
      }
      *(half8*)(ab + (size_t)row * 32 + SWZ(c, row)) = h;
    }
  };
  auto WLOAD = [&](int t, int buf) {
    _Float16* bb = lds + buf * CHUNK + ACH;
    int row = tid >> 2, c = tid & 3;
    int cs = (c ^ (row >> 1)) & 3;
    gload_lds16(B0 + (size_t)row * 1024 + t * 32 + cs * 8, bb + tid * 8);
    if (WSPLIT)
      gload_lds16(B1 + (size_t)row * 1024 + t * 32 + cs * 8,
                  bb + BCH + tid * 8);
  };
  auto COMPUTE = [&](int buf) {
    const _Float16* la = lds + buf * CHUNK;
    const _Float16* lb = la + ACH;
    half8 a[4], b0f[4], b1f[4];
#pragma unroll
    for (int mi = 0; mi < 4; ++mi) {
      int row = wm * 64 + mi * 16 + r16;
      a[mi] = *(const half8*)(la + row * 32 + SWZ(kg, row));
    }
#pragma unroll
    for (int ni = 0; ni < 4; ++ni) {
      int row = wn * 64 + ni * 16 + r16;
      int off = row * 32 + SWZ(kg, row);
      b0f[ni] = *(const half8*)(lb + off);
      if (WSPLIT) b1f[ni] = *(const half8*)(lb + BCH + off);
    }
    __builtin_amdgcn_s_setprio(1);
#pragma unroll
    for (int mi = 0; mi < 4; ++mi)
#pragma unroll
      for (int ni = 0; ni < 4; ++ni) {
        acc[mi][ni] = __builtin_amdgcn_mfma_f32_16x16x32_f16(
            a[mi], b0f[ni], acc[mi][ni], 0, 0, 0);
        if (WSPLIT)
          acc[mi][ni] = __builtin_amdgcn_mfma_f32_16x16x32_f16(
              a[mi], b1f[ni], acc[mi][ni], 0, 0, 0);
      }
    __builtin_amdgcn_s_setprio(0);
  };

  const int NS = 32;
  WLOAD(0, 0);
  ALOAD(0);
  asm volatile("s_waitcnt vmcnt(0)" ::: "memory");
  __builtin_amdgcn_sched_barrier(0);
  AWRITE(0);
  asm volatile("s_waitcnt lgkmcnt(0)" ::: "memory");
  FENCED_BARRIER();
  for (int t = 0; t < NS; ++t) {
    if (t + 1 < NS) {
      WLOAD(t + 1, (t + 1) & 1);
      ALOAD(t + 1);
    }
    COMPUTE(t & 1);
    if (t + 1 < NS) {
      asm volatile("s_waitcnt vmcnt(0)" ::: "memory");
      __builtin_amdgcn_sched_barrier(0);
      AWRITE((t + 1) & 1);
      asm volatile("s_waitcnt lgkmcnt(0)" ::: "memory");
      FENCED_BARRIER();
    }
  }

  float bcol[4];
#pragma unroll
  for (int ni = 0; ni < 4; ++ni) bcol[ni] = bias[n0 + wn * 64 + ni * 16 + r16];

  if (OUTMODE != 2) {
#pragma unroll
    for (int mi = 0; mi < 4; ++mi) {
      int row = m0 + wm * 64 + mi * 16 + kg * 4;
#pragma unroll
      for (int ni = 0; ni < 4; ++ni) {
        int col = n0 + wn * 64 + ni * 16 + r16;
#pragma unroll
        for (int j = 0; j < 4; ++j) {
          float v = acc[mi][ni][j] + bcol[ni];
          _Float16 h = (_Float16)v;
          OutHi[(size_t)(row + j) * 1024 + col] = h;
          if (OUTMODE == 0)
            OutLo[(size_t)(row + j) * 1024 + col] = (_Float16)(v - (float)h);
        }
      }
    }
  } else {
    __syncthreads();
    _Float16(*T)[256] = (_Float16(*)[256])lds;
#pragma unroll
    for (int mi = 0; mi < 4; ++mi) {
      int ml = wm * 64 + mi * 16 + kg * 4;
#pragma unroll
      for (int ni = 0; ni < 4; ++ni) {
        int nl = wn * 64 + ni * 16 + r16;
#pragma unroll
        for (int j = 0; j < 4; ++j)
          T[nl][ml + j] = (_Float16)(acc[mi][ni][j] + bcol[ni]);
      }
    }
    __syncthreads();
    const int b = m0 >> 11;
    const int s0 = m0 & 2047;
#pragma unroll
    for (int r = 0; r < 8; ++r) {
      int flat = tid + r * 512;
      int n = flat >> 5, c = flat & 31;
      half8 v = *(const half8*)&T[n][c * 8];
      *(half8*)(VtOut + (size_t)b * (1024 * 2048) + (size_t)(n0 + n) * 2048 +
                s0 + c * 8) = v;
    }
  }
}

// ---------------------------------------------------------------------------
// QK^T: ring-3 counted-vmcnt, tile 64x128, 256 thr / 4 waves (3 blocks/CU).
// 2176 causal tiles / 768 slots = 2.83 -> ~94% schedule balance (was 75%).
// Same per-output accumulation order (hi then lo per 32-chunk) -> logits
// bit-identical to rounds 7-10. Pad mask folded into epilogue (same fp32 add
// softmax previously did -> bit-identical).
// ---------------------------------------------------------------------------
__global__ __launch_bounds__(256, 3) void qk_eng(
    const _Float16* __restrict__ Qh, const _Float16* __restrict__ Ql,
    const _Float16* __restrict__ Kh, const int* __restrict__ pad,
    float* __restrict__ Lg, int bbase) {
  extern __shared__ _Float16 lds[];
  constexpr int CHUNK = 8192;  // A0 2048 | A1 2048 | B 4096 halves (16 KB)
  const int id = xcd_swz(blockIdx.x, gridDim.x);
  const int y = id / 272;
  int t = id % 272;
  int qt = 0, base = 0;
  while (t >= base + (qt >> 1) + 1) { base += (qt >> 1) + 1; ++qt; }
  const int kt = t - base;  // 128-col k tile, kt <= qt/2
  const int b = bbase + y;
  const size_t boff = (size_t)b * (2048 * 1024);
  const _Float16* A0 = Qh + boff + (size_t)(qt * 64) * 1024;
  const _Float16* A1 = Ql + boff + (size_t)(qt * 64) * 1024;
  const _Float16* B0 = Kh + boff + (size_t)(kt * 128) * 1024;
  const int tid = threadIdx.x;
  const int w = tid >> 6, lane = tid & 63;
  const int r16 = lane & 15, kg = lane >> 4;
  const int wn = w;  // 4 waves x 32 cols
  f32x4 acc[4][2];
  acc_zero42(acc);

  auto STAGE = [&](int t_, int buf) {
    _Float16* base_ = lds + buf * CHUNK;
    {
      int row = tid >> 2, c = tid & 3;  // 64 rows x 4 granules
      int cs = (c ^ (row >> 1)) & 3;
      size_t src = (size_t)row * 1024 + t_ * 32 + cs * 8;
      gload_lds16(A0 + src, base_ + tid * 8);
      gload_lds16(A1 + src, base_ + 2048 + tid * 8);
    }
#pragma unroll
    for (int j = 0; j < 2; ++j) {
      int g = tid + j * 256;
      int row = g >> 2, c = g & 3;  // 128 rows
      int cs = (c ^ (row >> 1)) & 3;
      gload_lds16(B0 + (size_t)row * 1024 + t_ * 32 + cs * 8,
                  base_ + 4096 + g * 8);
    }
  };
  auto COMPUTE = [&](int buf) {
    const _Float16* la = lds + buf * CHUNK;
    half8 a0[4], a1[4], bf[2];
#pragma unroll
    for (int mi = 0; mi < 4; ++mi) {
      int row = mi * 16 + r16;
      int off = row * 32 + SWZ(kg, row);
      a0[mi] = *(const half8*)(la + off);
      a1[mi] = *(const half8*)(la + 2048 + off);
    }
#pragma unroll
    for (int ni = 0; ni < 2; ++ni) {
      int row = wn * 32 + ni * 16 + r16;
      bf[ni] = *(const half8*)(la + 4096 + row * 32 + SWZ(kg, row));
    }
    __builtin_amdgcn_s_setprio(1);
#pragma unroll
    for (int mi = 0; mi < 4; ++mi)
#pragma unroll
      for (int ni = 0; ni < 2; ++ni) {
        acc[mi][ni] = __builtin_amdgcn_mfma_f32_16x16x32_f16(
            a0[mi], bf[ni], acc[mi][ni], 0, 0, 0);
        acc[mi][ni] = __builtin_amdgcn_mfma_f32_16x16x32_f16(
            a1[mi], bf[ni], acc[mi][ni], 0, 0, 0);
      }
    __builtin_amdgcn_s_setprio(0);
  };

  const int NS = 32;
  STAGE(0, 0);
  STAGE(1, 1);
  int tt = 0;
  for (; tt < NS - 1; ++tt) {
    asm volatile("s_waitcnt vmcnt(4)" ::: "memory");  // stage(tt) landed
    FENCED_BARRIER();
    if (tt + 2 < NS) STAGE(tt + 2, (tt + 2) % 3);
    COMPUTE(tt % 3);
  }
  asm volatile("s_waitcnt vmcnt(0)" ::: "memory");
  FENCED_BARRIER();
  COMPUTE(tt % 3);

  float* L = Lg + (size_t)y * (2048 * 2048);
  const int* pb = pad + (size_t)b * 2048;
#pragma unroll
  for (int ni = 0; ni < 2; ++ni) {
    int col = kt * 128 + wn * 32 + ni * 16 + r16;
    const float padd = (pb[col] == 0) ? -1.0e9f : 0.0f;
#pragma unroll
    for (int mi = 0; mi < 4; ++mi) {
      int row = qt * 64 + mi * 16 + kg * 4;
#pragma unroll
      for (int j = 0; j < 4; ++j)
        L[(size_t)(row + j) * 2048 + col] = acc[mi][ni][j] + padd;
    }
  }
}

// ---------------------------------------------------------------------------
// PV: ring-3 counted-vmcnt, tile 128x128 (validated round 9/10), now with
// perfectly balanced pairing: block g handles tiles g and N-1-g (work
// (qt+1)+(16-qt) = const 17 K-steps per block).
// ---------------------------------------------------------------------------
__global__ __launch_bounds__(512, 4) void pv_eng(
    const float* __restrict__ Lg, const _Float16* __restrict__ Vt,
    float* __restrict__ Out, int bbase, int ntiles) {
  extern __shared__ _Float16 lds[];
  constexpr int CHUNK = 8192;  // A 4096 | B 4096 halves
  const int g0 = xcd_swz(blockIdx.x, gridDim.x);
  const int tid = threadIdx.x;
  const int w = tid >> 6, lane = tid & 63;
  const int wm = w >> 2, wn = w & 3;
  const int r16 = lane & 15, kg = lane >> 4;

  for (int half = 0; half < 2; ++half) {
    const int idt = half ? (ntiles - 1 - g0) : g0;
    const int y = idt >> 7;
    const int qt = (idt & 127) >> 3, nt = idt & 7;
    const int b = bbase + y;
    const _Float16* P = (const _Float16*)(Lg + (size_t)y * (2048 * 2048));
    const _Float16* A0 = P + (size_t)(qt * 128) * 4096;
    const _Float16* B0 =
        Vt + (size_t)b * (1024 * 2048) + (size_t)(nt * 128) * 2048;
    const int NS = (qt + 1) * 4;
    f32x4 acc[4][2];
    acc_zero42(acc);

    auto STAGE = [&](int t_, int buf) {
      _Float16* base_ = lds + buf * CHUNK;
      int row = tid >> 2, c = tid & 3;
      int cs = (c ^ (row >> 1)) & 3;
      gload_lds16(A0 + (size_t)row * 4096 + t_ * 32 + cs * 8, base_ + tid * 8);
      gload_lds16(B0 + (size_t)row * 2048 + t_ * 32 + cs * 8,
                  base_ + 4096 + tid * 8);
    };
    auto COMPUTE = [&](int buf) {
      const _Float16* la = lds + buf * CHUNK;
      half8 a[4], bf[2];
#pragma unroll
      for (int mi = 0; mi < 4; ++mi) {
        int row = wm * 64 + mi * 16 + r16;
        a[mi] = *(const half8*)(la + row * 32 + SWZ(kg, row));
      }
#pragma unroll
      for (int ni = 0; ni < 2; ++ni) {
        int row = wn * 32 + ni * 16 + r16;
        bf[ni] = *(const half8*)(la + 4096 + row * 32 + SWZ(kg, row));
      }
      __builtin_amdgcn_s_setprio(1);
#pragma unroll
      for (int mi = 0; mi < 4; ++mi)
#pragma unroll
        for (int ni = 0; ni < 2; ++ni)
          acc[mi][ni] = __builtin_amdgcn_mfma_f32_16x16x32_f16(
              a[mi], bf[ni], acc[mi][ni], 0, 0, 0);
      __builtin_amdgcn_s_setprio(0);
    };

    STAGE(0, 0);
    STAGE(1, 1);
    int tt = 0;
    for (; tt < NS - 1; ++tt) {
      asm volatile("s_waitcnt vmcnt(2)" ::: "memory");
      FENCED_BARRIER();
      if (tt + 2 < NS) STAGE(tt + 2, (tt + 2) % 3);
      COMPUTE(tt % 3);
    }
    asm volatile("s_waitcnt vmcnt(0)" ::: "memory");
    FENCED_BARRIER();
    COMPUTE(tt % 3);

#pragma unroll
    for (int mi = 0; mi < 4; ++mi) {
      int row = qt * 128 + wm * 64 + mi * 16 + kg * 4;
#pragma unroll
      for (int ni = 0; ni < 2; ++ni) {
        int col = nt * 128 + wn * 32 + ni * 16 + r16;
#pragma unroll
        for (int j = 0; j < 4; ++j)
          Out[(size_t)(b * 2048 + row + j) * 1024 + col] = acc[mi][ni][j];
      }
    }
    if (half == 0) {
      // make LDS safe to reuse for the second tile
      asm volatile("s_waitcnt vmcnt(0) lgkmcnt(0)" ::: "memory");
      FENCED_BARRIER();
    }
  }
}

// ---------------------------------------------------------------------------
// Row softmax; pad mask already folded into L by qk epilogue.
// In-place fp16 P; zero-fill to 256-col boundary.
// ---------------------------------------------------------------------------
__global__ __launch_bounds__(256) void softmax_kernel(float* __restrict__ Lg,
                                                      int bbase) {
  const int q = blockIdx.x;
  const int y = blockIdx.y;
  const int tid = threadIdx.x;
  float* row = Lg + (size_t)y * (2048 * 2048) + (size_t)q * 2048;
  _Float16* prow = (_Float16*)row;
  const int kend = ((q >> 8) + 1) << 8;
  float v[8];
  int nv = 0;
  float mx = -3.0e38f;
  for (int k = tid; k <= q; k += 256) {
    float l = row[k];
    v[nv++] = l;
    mx = fmaxf(mx, l);
  }
  __shared__ float red[4];
  for (int o = 32; o; o >>= 1) mx = fmaxf(mx, __shfl_xor(mx, o));
  if ((tid & 63) == 0) red[tid >> 6] = mx;
  __syncthreads();
  mx = fmaxf(fmaxf(red[0], red[1]), fmaxf(red[2], red[3]));
  __syncthreads();
  float s = 0.f;
  for (int i = 0; i < nv; ++i) s += expf(v[i] - mx);
  for (int o = 32; o; o >>= 1) s += __shfl_xor(s, o);
  if ((tid & 63) == 0) red[tid >> 6] = s;
  __syncthreads();
  s = red[0] + red[1] + red[2] + red[3];
  const float inv = 1.0f / s;
  int i = 0;
  for (int k = tid; k <= q; k += 256) {
    prow[k] = (_Float16)(expf(v[i] - mx) * inv);
    ++i;
  }
  for (int k = q + 1 + tid; k < kend; k += 256) prow[k] = (_Float16)0.0f;
}

// ---------------------------------------------------------------------------
// Fixup for degenerate rows q < f[b] (validated rounds 4-10, verbatim).
// ---------------------------------------------------------------------------
__global__ __launch_bounds__(512) void fix_f(const int* __restrict__ pad,
                                             int* __restrict__ fb) {
  const int b = threadIdx.x >> 6, k = threadIdx.x & 63;
  unsigned long long m = __ballot(pad[b * 2048 + k] != 0);
  if (k == 0) fb[b] = m ? (__ffsll((long long)m) - 1) : 64;
}

__global__ __launch_bounds__(256) void fix_qrow2(
    const float* __restrict__ xQ, const float* __restrict__ Wq,
    const float* __restrict__ bq, const int* __restrict__ fb,
    float* __restrict__ Qrow) {
  const int b = blockIdx.y;
  const int f = fb[b];
  const int tid = threadIdx.x;
  const int e = blockIdx.x * 16 + (tid >> 4);
  const int l16 = tid & 15;
  __shared__ float xq[1024];
  for (int q = 0; q < f; ++q) {
    *(f4*)&xq[tid * 4] = ((const f4*)(xQ + (size_t)(b * 2048 + q) * 1024))[tid];
    __syncthreads();
    float a = 0.f;
#pragma unroll
    for (int it = 0; it < 16; ++it) {
      int d = l16 * 4 + it * 64;
      f4 ww = *(const f4*)(Wq + (size_t)e * 1024 + d);
      a += xq[d] * ww[0] + xq[d + 1] * ww[1] + xq[d + 2] * ww[2] +
           xq[d + 3] * ww[3];
    }
    for (int o = 8; o; o >>= 1) a += __shfl_xor(a, o);
    if (l16 == 0) Qrow[((size_t)b * 64 + q) * 1024 + e] = a + bq[e];
    __syncthreads();
  }
}

__global__ __launch_bounds__(256) void fix_qb0(const float* __restrict__ bk,
                                               const int* __restrict__ fb,
                                               const float* __restrict__ Qrow,
                                               float* __restrict__ qb0) {
  const int q = blockIdx.x, b = blockIdx.y;
  if (q >= fb[b]) return;
  const int tid = threadIdx.x;
  const float* qr = Qrow + ((size_t)b * 64 + q) * 1024;
  float p = 0.f;
  for (int e = tid; e < 1024; e += 256) p += qr[e] * bk[e];
  __shared__ float red[4];
  for (int o = 32; o; o >>= 1) p += __shfl_xor(p, o);
  if ((tid & 63) == 0) red[tid >> 6] = p;
  __syncthreads();
  if (tid == 0) qb0[b * 64 + q] = red[0] + red[1] + red[2] + red[3];
}

__global__ __launch_bounds__(256) void fix_g2(const float* __restrict__ Wk,
                                              const int* __restrict__ fb,
                                              const float* __restrict__ Qrow,
                                              float* __restrict__ Gpart) {
  const int b = blockIdx.y;
  const int f = fb[b];
  const int tid = threadIdx.x;
  const int ddblk = blockIdx.x & 3, es = blockIdx.x >> 2;
  const int dd = ddblk * 256 + tid;
  __shared__ float qc[128];
  for (int q = 0; q < f; ++q) {
    if (tid < 32)
      *(f4*)&qc[tid * 4] =
          ((const f4*)(Qrow + ((size_t)b * 64 + q) * 1024 + es * 128))[tid];
    __syncthreads();
    float g = 0.f;
    for (int e = 0; e < 128; ++e)
      g += qc[e] * Wk[(size_t)(es * 128 + e) * 1024 + dd];
    Gpart[(((size_t)es * 8 + b) * 64 + q) * 1024 + dd] = g;
    __syncthreads();
  }
}

__global__ __launch_bounds__(256) void fix_logit2(
    const float* __restrict__ xK, const int* __restrict__ pad,
    const int* __restrict__ fb, const float* __restrict__ Gpart,
    const float* __restrict__ qb0, float* __restrict__ lrow) {
  const int b = blockIdx.y;
  const int f = fb[b];
  const int tid = threadIdx.x;
  const int k = blockIdx.x * 16 + (tid >> 4);
  const int l16 = tid & 15;
  __shared__ float Gs[1024];
  for (int q = 0; q < f; ++q) {
    f4 s = (f4)0.0f;
#pragma unroll
    for (int es = 0; es < 8; ++es)
      s += ((const f4*)(Gpart + (((size_t)es * 8 + b) * 64 + q) * 1024))[tid];
    *(f4*)&Gs[tid * 4] = s;
    __syncthreads();
    float a = 0.f;
#pragma unroll
    for (int it = 0; it < 16; ++it) {
      int d = l16 * 4 + it * 64;
      f4 x = *(const f4*)(xK + (size_t)(b * 2048 + k) * 1024 + d);
      a += x[0] * Gs[d] + x[1] * Gs[d + 1] + x[2] * Gs[d + 2] +
           x[3] * Gs[d + 3];
    }
    for (int o = 8; o; o >>= 1) a += __shfl_xor(a, o);
    if (l16 == 0) {
      float l = a + qb0[b * 64 + q];
      if (pad[b * 2048 + k] == 0) l += -1.0e9f;
      if (k > q) l += -1.0e9f;
      lrow[((size_t)b * 64 + q) * 2048 + k] = l;
    }
    __syncthreads();
  }
}

__global__ __launch_bounds__(256) void fix_sm(const int* __restrict__ fb,
                                              float* __restrict__ lrow,
                                              float* __restrict__ srow) {
  const int q = blockIdx.x, b = blockIdx.y;
  if (q >= fb[b]) return;
  const int tid = threadIdx.x;
  float* row = lrow + ((size_t)b * 64 + q) * 2048;
  float v[8];
  float mx = -3.0e38f;
#pragma unroll
  for (int i = 0; i < 8; ++i) {
    v[i] = row[tid + i * 256];
    mx = fmaxf(mx, v[i]);
  }
  __shared__ float red[4];
  for (int o = 32; o; o >>= 1) mx = fmaxf(mx, __shfl_xor(mx, o));
  if ((tid & 63) == 0) red[tid >> 6] = mx;
  __syncthreads();
  mx = fmaxf(fmaxf(red[0], red[1]), fmaxf(red[2], red[3]));
  __syncthreads();
  float s = 0.f;
#pragma unroll
  for (int i = 0; i < 8; ++i) {
    v[i] = expf(v[i] - mx);
    s += v[i];
  }
#pragma unroll
  for (int i = 0; i < 8; ++i) row[tid + i * 256] = v[i];
  for (int o = 32; o; o >>= 1) s += __shfl_xor(s, o);
  if ((tid & 63) == 0) red[tid >> 6] = s;
  __syncthreads();
  if (tid == 0) srow[b * 64 + q] = red[0] + red[1] + red[2] + red[3];
}

__global__ __launch_bounds__(256) void fix_pv2(
    const _Float16* __restrict__ Vt, const int* __restrict__ fb,
    const float* __restrict__ lrow, const float* __restrict__ srow,
    float* __restrict__ Out) {
  const int b = blockIdx.y;
  const int f = fb[b];
  const int tid = threadIdx.x;
  const int d = blockIdx.x * 16 + (tid >> 4);
  const int l16 = tid & 15;
  __shared__ float ps[2048];
  for (int q = 0; q < f; ++q) {
    const f4* src = (const f4*)(lrow + ((size_t)b * 64 + q) * 2048);
    *(f4*)&ps[tid * 8] = src[tid * 2];
    *(f4*)&ps[tid * 8 + 4] = src[tid * 2 + 1];
    __syncthreads();
    float o = 0.f;
#pragma unroll
    for (int it = 0; it < 16; ++it) {
      int k = l16 * 8 + it * 128;
      half8 vv = *(const half8*)(Vt + (size_t)b * (1024 * 2048) +
                                 (size_t)d * 2048 + k);
      o += (float)vv[0] * ps[k] + (float)vv[1] * ps[k + 1] +
           (float)vv[2] * ps[k + 2] + (float)vv[3] * ps[k + 3] +
           (float)vv[4] * ps[k + 4] + (float)vv[5] * ps[k + 5] +
           (float)vv[6] * ps[k + 6] + (float)vv[7] * ps[k + 7];
    }
    for (int of = 8; of; of >>= 1) o += __shfl_xor(o, of);
    if (l16 == 0)
      Out[(size_t)(b * 2048 + q) * 1024 + d] = o * (1.0f / srow[b * 64 + q]);
    __syncthreads();
  }
}

// ---------------------------------------------------------------------------
extern "C" void kernel_launch(void* const* d_in, const int* in_sizes, int n_in,
                              void* d_out, int out_size, void* d_ws,
                              size_t ws_size, hipStream_t stream) {
  const float* xQ = (const float*)d_in[0];
  const float* xK = (const float*)d_in[1];
  const float* xV = (const float*)d_in[2];
  const int* pad = (const int*)d_in[3];
  const float* Wq = (const float*)d_in[5];
  const float* bq = (const float*)d_in[6];
  const float* Wk = (const float*)d_in[7];
  const float* bk = (const float*)d_in[8];
  const float* Wv = (const float*)d_in[9];
  const float* bv = (const float*)d_in[10];
  float* Out = (float*)d_out;

  const size_t MB = (size_t)1 << 20;
  char* wsb = (char*)d_ws;
  // Persistent: Qh [0,32) Ql [32,64) Kh [64,96) Vt [96,128); Lg at 128.
  _Float16* Qh = (_Float16*)(wsb);
  _Float16* Ql = (_Float16*)(wsb + 32 * MB);
  _Float16* Kh = (_Float16*)(wsb + 64 * MB);
  _Float16* Vt = (_Float16*)(wsb + 96 * MB);
  float* Lg = (float*)(wsb + 128 * MB);

  size_t avail = (ws_size > 128 * MB) ? ws_size - 128 * MB : 0;
  int G = (int)(avail / (16 * MB));
  if (G > 8) G = 8;
  if (G < 1) G = 1;

  const int SM_P1 = 73728;  // proj3 WSPLIT=1: 3 x 24KB
  const int SM_P0 = 49152;  // proj3 WSPLIT=0: 3 x 16KB
  const int SM_F = 65536;   // proj_fused fallback
  const int SM_QK = 49152;  // 3 x 16KB
  const int SM_PV = 49152;  // 3 x 16KB
  (void)hipFuncSetAttribute((const void*)&proj3<1, 0>,
                            hipFuncAttributeMaxDynamicSharedMemorySize, SM_P1);
  (void)hipFuncSetAttribute((const void*)&proj3<1, 1>,
                            hipFuncAttributeMaxDynamicSharedMemorySize, SM_P1);
  (void)hipFuncSetAttribute((const void*)&proj3<0, 2>,
                            hipFuncAttributeMaxDynamicSharedMemorySize, SM_P0);
  (void)hipFuncSetAttribute((const void*)&proj_fused<1, 0>,
                            hipFuncAttributeMaxDynamicSharedMemorySize, SM_F);
  (void)hipFuncSetAttribute((const void*)&proj_fused<1, 1>,
                            hipFuncAttributeMaxDynamicSharedMemorySize, SM_F);
  (void)hipFuncSetAttribute((const void*)&proj_fused<0, 2>,
                            hipFuncAttributeMaxDynamicSharedMemorySize, SM_F);
  (void)hipFuncSetAttribute((const void*)&qk_eng,
                            hipFuncAttributeMaxDynamicSharedMemorySize, SM_QK);
  (void)hipFuncSetAttribute((const void*)&pv_eng,
                            hipFuncAttributeMaxDynamicSharedMemorySize, SM_PV);

  dim3 blk(256), eblk(512);

  if (ws_size >= 165 * MB) {
    // Fast path (validated round 10): pre-convert X + ring-3 proj3.
    {
      _Float16* sX = (_Float16*)(wsb);
      _Float16* sW = (_Float16*)(wsb + 32 * MB);
      cvt_plain<<<dim3(2048), blk, 0, stream>>>(xV, sX, 4194304);
      cvt_plain<<<dim3(1024), blk, 0, stream>>>(Wv, sW, 262144);
      proj3<0, 2><<<dim3(1024), eblk, SM_P0, stream>>>(sX, sW, sW, bv, nullptr,
                                                       nullptr, Vt);
    }
    {
      _Float16* sX = (_Float16*)(wsb);
      _Float16* sWh = (_Float16*)(wsb + 32 * MB);
      _Float16* sWl = (_Float16*)(wsb + 34 * MB);
      cvt_plain<<<dim3(2048), blk, 0, stream>>>(xK, sX, 4194304);
      cvt_split<<<dim3(1024), blk, 0, stream>>>(Wk, sWh, sWl, 262144);
      proj3<1, 1><<<dim3(1024), eblk, SM_P1, stream>>>(sX, sWh, sWl, bk, Kh,
                                                       nullptr, nullptr);
    }
    {
      _Float16* sX = (_Float16*)(wsb + 128 * MB);
      _Float16* sWh = (_Float16*)(wsb + 160 * MB);
      _Float16* sWl = (_Float16*)(wsb + 162 * MB);
      cvt_plain<<<dim3(2048), blk, 0, stream>>>(xQ, sX, 4194304);
      cvt_split<<<dim3(1024), blk, 0, stream>>>(Wq, sWh, sWl, 262144);
      proj3<1, 0><<<dim3(1024), eblk, SM_P1, stream>>>(sX, sWh, sWl, bq, Qh,
                                                       Ql, nullptr);
    }
  } else {
    _Float16* Wqh = (_Float16*)(wsb + 128 * MB);
    _Float16* Wql = (_Float16*)(wsb + 130 * MB);
    _Float16* Wkh = (_Float16*)(wsb + 132 * MB);
    _Float16* Wkl = (_Float16*)(wsb + 134 * MB);
    _Float16* Wvh = (_Float16*)(wsb + 136 * MB);
    cvt_split<<<dim3(1024), blk, 0, stream>>>(Wq, Wqh, Wql, 262144);
    cvt_split<<<dim3(1024), blk, 0, stream>>>(Wk, Wkh, Wkl, 262144);
    cvt_plain<<<dim3(1024), blk, 0, stream>>>(Wv, Wvh, 262144);
    proj_fused<0, 2><<<dim3(512), eblk, SM_F, stream>>>(xV, Wvh, Wvh, bv,
                                                        nullptr, nullptr, Vt);
    proj_fused<1, 1><<<dim3(512), eblk, SM_F, stream>>>(xK, Wkh, Wkl, bk, Kh,
                                                        nullptr, nullptr);
    proj_fused<1, 0><<<dim3(512), eblk, SM_F, stream>>>(xQ, Wqh, Wql, bq, Qh,
                                                        Ql, nullptr);
  }

  // --- Attention ---
  for (int bbase = 0; bbase < 8; bbase += G) {
    int nb = (8 - bbase < G) ? (8 - bbase) : G;
    qk_eng<<<dim3(272 * nb), blk, SM_QK, stream>>>(Qh, Ql, Kh, pad, Lg, bbase);
    softmax_kernel<<<dim3(2048, nb), blk, 0, stream>>>(Lg, bbase);
    pv_eng<<<dim3(64 * nb), eblk, SM_PV, stream>>>(Lg, Vt, Out, bbase,
                                                   128 * nb);
  }

  // --- Fixup: scratch in [0,24) MB (Qh dead after last qk) ---
  int* fb = (int*)(wsb);
  float* qb0 = (float*)(wsb + 4 * 1024);
  float* srow = (float*)(wsb + 8 * 1024);
  float* Qrow = (float*)(wsb + 1 * MB);   // 2 MB
  float* Gpart = (float*)(wsb + 4 * MB);  // 16 MB
  float* lrow = (float*)(wsb + 20 * MB);  // 4 MB

  fix_f<<<dim3(1), dim3(512), 0, stream>>>(pad, fb);
  fix_qrow2<<<dim3(64, 8), blk, 0, stream>>>(xQ, Wq, bq, fb, Qrow);
  fix_qb0<<<dim3(64, 8), blk, 0, stream>>>(bk, fb, Qrow, qb0);
  fix_g2<<<dim3(32, 8), blk, 0, stream>>>(Wk, fb, Qrow, Gpart);
  fix_logit2<<<dim3(128, 8), blk, 0, stream>>>(xK, pad, fb, Gpart, qb0, lrow);
  fix_sm<<<dim3(64, 8), blk, 0, stream>>>(fb, lrow, srow);
  fix_pv2<<<dim3(64, 8), blk, 0, stream>>>(Vt, fb, lrow, srow, Out);
}

// Round 12
// 496.100 us; speedup vs baseline: 1.0103x; 1.0103x over previous
//
#include <hip/hip_runtime.h>

typedef __attribute__((ext_vector_type(4))) float f4;
typedef __attribute__((ext_vector_type(4))) float f32x4;
typedef _Float16 half8 __attribute__((ext_vector_type(8)));

#define DEVI static __device__ __forceinline__

DEVI void gload_lds16(const void* g, void* l) {
  __builtin_amdgcn_global_load_lds(
      (const __attribute__((address_space(1))) void*)g,
      (__attribute__((address_space(3))) void*)l, 16, 0, 0);
}

// bijective XCD swizzle (m204)
DEVI int xcd_swz(int id, int n) {
  int q = n >> 3, r = n & 7;
  int x = id & 7, c = id >> 3;
  return (x < r ? x * (q + 1) : r * (q + 1) + (x - r) * q) + c;
}

#define FENCED_BARRIER()                \
  __builtin_amdgcn_sched_barrier(0);    \
  __builtin_amdgcn_s_barrier();         \
  __builtin_amdgcn_sched_barrier(0);

#define SWZ(kgv, rowv) ((((kgv) ^ ((rowv) >> 1)) & 3) * 8)

// ---------------------------------------------------------------------------
// fp32 -> fp16 conversions.
// ---------------------------------------------------------------------------
__global__ __launch_bounds__(256) void cvt_plain(const float* __restrict__ X,
                                                 _Float16* __restrict__ H,
                                                 int n4) {
  int i = blockIdx.x * 256 + threadIdx.x;
  const int stride = gridDim.x * 256;
  typedef _Float16 half4v __attribute__((ext_vector_type(4)));
  for (; i < n4; i += stride) {
    f4 x = ((const f4*)X)[i];
    half4v h;
#pragma unroll
    for (int j = 0; j < 4; ++j) h[j] = (_Float16)x[j];
    ((half4v*)H)[i] = h;
  }
}

__global__ __launch_bounds__(256) void cvt_split(const float* __restrict__ X,
                                                 _Float16* __restrict__ H,
                                                 _Float16* __restrict__ L,
                                                 int n4) {
  int i = blockIdx.x * 256 + threadIdx.x;
  const int stride = gridDim.x * 256;
  typedef _Float16 half4v __attribute__((ext_vector_type(4)));
  for (; i < n4; i += stride) {
    f4 x = ((const f4*)X)[i];
    half4v h, l;
#pragma unroll
    for (int j = 0; j < 4; ++j) {
      h[j] = (_Float16)x[j];
      l[j] = (_Float16)(x[j] - (float)h[j]);
    }
    ((half4v*)H)[i] = h;
    ((half4v*)L)[i] = l;
  }
}

DEVI void acc_zero44(f32x4 (&acc)[4][4]) {
#pragma unroll
  for (int i = 0; i < 4; ++i)
#pragma unroll
    for (int j = 0; j < 4; ++j) acc[i][j] = (f32x4)0.0f;
}
DEVI void acc_zero42(f32x4 (&acc)[4][2]) {
#pragma unroll
  for (int i = 0; i < 4; ++i)
#pragma unroll
    for (int j = 0; j < 2; ++j) acc[i][j] = (f32x4)0.0f;
}

// ---------------------------------------------------------------------------
// proj3: ring-3 counted-vmcnt projection engine (validated round 10).
// Tile 128x128, 512 thr / 8 waves, wave tile 64x32. OUTMODE 0=Q 1=K 2=Vt.
// ---------------------------------------------------------------------------
template <int WSPLIT, int OUTMODE>
__global__ __launch_bounds__(512, 4) void proj3(
    const _Float16* __restrict__ X, const _Float16* __restrict__ Wh,
    const _Float16* __restrict__ Wl, const float* __restrict__ bias,
    _Float16* __restrict__ OutHi, _Float16* __restrict__ OutLo,
    _Float16* __restrict__ VtOut) {
  extern __shared__ _Float16 lds[];
  constexpr int ACH = 128 * 32;
  constexpr int BCH = 128 * 32;
  constexpr int CHUNK = ACH + BCH * (1 + WSPLIT);
  const int id = xcd_swz(blockIdx.x, gridDim.x);
  const int m0 = (id >> 3) * 128, n0 = (id & 7) * 128;
  const _Float16* A0 = X + (size_t)m0 * 1024;
  const _Float16* B0 = Wh + (size_t)n0 * 1024;
  const _Float16* B1 = Wl + (size_t)n0 * 1024;
  const int tid = threadIdx.x;
  const int w = tid >> 6, lane = tid & 63;
  const int wm = w >> 2, wn = w & 3;
  const int r16 = lane & 15, kg = lane >> 4;
  f32x4 acc[4][2];
  acc_zero42(acc);

  auto STAGE = [&](int t, int buf) {
    _Float16* base = lds + buf * CHUNK;
    int row = tid >> 2, c = tid & 3;
    int cs = (c ^ (row >> 1)) & 3;
    size_t src = (size_t)row * 1024 + t * 32 + cs * 8;
    gload_lds16(A0 + src, base + tid * 8);
    gload_lds16(B0 + src, base + ACH + tid * 8);
    if (WSPLIT) gload_lds16(B1 + src, base + ACH + BCH + tid * 8);
  };
  auto COMPUTE = [&](int buf) {
    const _Float16* la = lds + buf * CHUNK;
    const _Float16* lb = la + ACH;
    half8 a[4], b0f[2], b1f[2];
#pragma unroll
    for (int mi = 0; mi < 4; ++mi) {
      int row = wm * 64 + mi * 16 + r16;
      a[mi] = *(const half8*)(la + row * 32 + SWZ(kg, row));
    }
#pragma unroll
    for (int ni = 0; ni < 2; ++ni) {
      int row = wn * 32 + ni * 16 + r16;
      int off = row * 32 + SWZ(kg, row);
      b0f[ni] = *(const half8*)(lb + off);
      if (WSPLIT) b1f[ni] = *(const half8*)(lb + BCH + off);
    }
    __builtin_amdgcn_s_setprio(1);
#pragma unroll
    for (int mi = 0; mi < 4; ++mi)
#pragma unroll
      for (int ni = 0; ni < 2; ++ni) {
        acc[mi][ni] = __builtin_amdgcn_mfma_f32_16x16x32_f16(
            a[mi], b0f[ni], acc[mi][ni], 0, 0, 0);
        if (WSPLIT)
          acc[mi][ni] = __builtin_amdgcn_mfma_f32_16x16x32_f16(
              a[mi], b1f[ni], acc[mi][ni], 0, 0, 0);
      }
    __builtin_amdgcn_s_setprio(0);
  };

  const int NS = 32;
  STAGE(0, 0);
  STAGE(1, 1);
  int tt = 0;
  for (; tt < NS - 1; ++tt) {
    if constexpr (WSPLIT)
      asm volatile("s_waitcnt vmcnt(3)" ::: "memory");
    else
      asm volatile("s_waitcnt vmcnt(2)" ::: "memory");
    FENCED_BARRIER();
    if (tt + 2 < NS) STAGE(tt + 2, (tt + 2) % 3);
    COMPUTE(tt % 3);
  }
  asm volatile("s_waitcnt vmcnt(0)" ::: "memory");
  FENCED_BARRIER();
  COMPUTE(tt % 3);

  float bcol[2];
#pragma unroll
  for (int ni = 0; ni < 2; ++ni) bcol[ni] = bias[n0 + wn * 32 + ni * 16 + r16];

  if (OUTMODE != 2) {
#pragma unroll
    for (int mi = 0; mi < 4; ++mi) {
      int row = m0 + wm * 64 + mi * 16 + kg * 4;
#pragma unroll
      for (int ni = 0; ni < 2; ++ni) {
        int col = n0 + wn * 32 + ni * 16 + r16;
#pragma unroll
        for (int j = 0; j < 4; ++j) {
          float v = acc[mi][ni][j] + bcol[ni];
          _Float16 h = (_Float16)v;
          OutHi[(size_t)(row + j) * 1024 + col] = h;
          if (OUTMODE == 0)
            OutLo[(size_t)(row + j) * 1024 + col] = (_Float16)(v - (float)h);
        }
      }
    }
  } else {
    __syncthreads();  // ring done; reuse LDS as transpose buffer (32 KB)
    _Float16(*T)[128] = (_Float16(*)[128])lds;
#pragma unroll
    for (int mi = 0; mi < 4; ++mi) {
      int ml = wm * 64 + mi * 16 + kg * 4;
#pragma unroll
      for (int ni = 0; ni < 2; ++ni) {
        int nl = wn * 32 + ni * 16 + r16;
#pragma unroll
        for (int j = 0; j < 4; ++j)
          T[nl][ml + j] = (_Float16)(acc[mi][ni][j] + bcol[ni]);
      }
    }
    __syncthreads();
    const int b = m0 >> 11;
    const int s0 = m0 & 2047;
#pragma unroll
    for (int r = 0; r < 4; ++r) {
      int flat = tid + r * 512;
      int n = flat >> 4, c = flat & 15;
      half8 v = *(const half8*)&T[n][c * 8];
      *(half8*)(VtOut + (size_t)b * (1024 * 2048) + (size_t)(n0 + n) * 2048 +
                s0 + c * 8) = v;
    }
  }
}

// ---------------------------------------------------------------------------
// Fused-cvt projection (fallback when ws is small). Validated round 9.
// ---------------------------------------------------------------------------
template <int WSPLIT, int OUTMODE>
__global__ __launch_bounds__(512, 2) void proj_fused(
    const float* __restrict__ X, const _Float16* __restrict__ Wh,
    const _Float16* __restrict__ Wl, const float* __restrict__ bias,
    _Float16* __restrict__ OutHi, _Float16* __restrict__ OutLo,
    _Float16* __restrict__ VtOut) {
  extern __shared__ _Float16 lds[];
  constexpr int ACH = 256 * 32;
  constexpr int BCH = 128 * 32;
  constexpr int CHUNK = ACH + BCH * (1 + WSPLIT);
  const int id = xcd_swz(blockIdx.x, gridDim.x);
  const int m0 = (id >> 3) * 256, n0 = (id & 7) * 128;
  const float* A = X + (size_t)m0 * 1024;
  const _Float16* B0 = Wh + (size_t)n0 * 1024;
  const _Float16* B1 = Wl + (size_t)n0 * 1024;
  const int tid = threadIdx.x;
  const int w = tid >> 6, lane = tid & 63;
  const int wm = w >> 1, wn = w & 1;
  const int r16 = lane & 15, kg = lane >> 4;
  f32x4 acc[4][4];
  acc_zero44(acc);
  f4 ra[4];

  auto ALOAD = [&](int t) {
#pragma unroll
    for (int j = 0; j < 2; ++j) {
      int g = tid + j * 512;
      int row = g >> 2, c = g & 3;
      const float* src = A + (size_t)row * 1024 + t * 32 + c * 8;
      ra[2 * j] = *(const f4*)src;
      ra[2 * j + 1] = *(const f4*)(src + 4);
    }
  };
  auto AWRITE = [&](int buf) {
    _Float16* ab = lds + buf * CHUNK;
#pragma unroll
    for (int j = 0; j < 2; ++j) {
      int g = tid + j * 512;
      int row = g >> 2, c = g & 3;
      half8 h;
#pragma unroll
      for (int e = 0; e < 4; ++e) {
        h[e] = (_Float16)ra[2 * j][e];
        h[e + 4] = (_Float16)ra[2 * j + 1][e];
      }
      *(half8*)(ab + (size_t)row * 32 + SWZ(c, row)) = h;
    }
  };
  auto WLOAD = [&](int t, int buf) {
    _Float16* bb = lds + buf * CHUNK + ACH;
    int row = tid >> 2, c = tid & 3;
    int cs = (c ^ (row >> 1)) & 3;
    gload_lds16(B0 + (size_t)row * 1024 + t * 32 + cs * 8, bb + tid * 8);
    if (WSPLIT)
      gload_lds16(B1 + (size_t)row * 1024 + t * 32 + cs * 8,
                  bb + BCH + tid * 8);
  };
  auto COMPUTE = [&](int buf) {
    const _Float16* la = lds + buf * CHUNK;
    const _Float16* lb = la + ACH;
    half8 a[4], b0f[4], b1f[4];
#pragma unroll
    for (int mi = 0; mi < 4; ++mi) {
      int row = wm * 64 + mi * 16 + r16;
      a[mi] = *(const half8*)(la + row * 32 + SWZ(kg, row));
    }
#pragma unroll
    for (int ni = 0; ni < 4; ++ni) {
      int row = wn * 64 + ni * 16 + r16;
      int off = row * 32 + SWZ(kg, row);
      b0f[ni] = *(const half8*)(lb + off);
      if (WSPLIT) b1f[ni] = *(const half8*)(lb + BCH + off);
    }
    __builtin_amdgcn_s_setprio(1);
#pragma unroll
    for (int mi = 0; mi < 4; ++mi)
#pragma unroll
      for (int ni = 0; ni < 4; ++ni) {
        acc[mi][ni] = __builtin_amdgcn_mfma_f32_16x16x32_f16(
            a[mi], b0f[ni], acc[mi][ni], 0, 0, 0);
        if (WSPLIT)
          acc[mi][ni] = __builtin_amdgcn_mfma_f32_16x16x32_f16(
              a[mi], b1f[ni], acc[mi][ni], 0, 0, 0);
      }
    __builtin_amdgcn_s_setprio(0);
  };

  const int NS = 32;
  WLOAD(0, 0);
  ALOAD(0);
  asm volatile("s_waitcnt vmcnt(0)" ::: "memory");
  __builtin_amdgcn_sched_barrier(0);
  AWRITE(0);
  asm volatile("s_waitcnt lgkmcnt(0)" ::: "memory");
  FENCED_BARRIER();
  for (int t = 0; t < NS; ++t) {
    if (t + 1 < NS) {
      WLOAD(t + 1, (t + 1) & 1);
      ALOAD(t + 1);
    }
    COMPUTE(t & 1);
    if (t + 1 < NS) {
      asm volatile("s_waitcnt vmcnt(0)" ::: "memory");
      __builtin_amdgcn_sched_barrier(0);
      AWRITE((t + 1) & 1);
      asm volatile("s_waitcnt lgkmcnt(0)" ::: "memory");
      FENCED_BARRIER();
    }
  }

  float bcol[4];
#pragma unroll
  for (int ni = 0; ni < 4; ++ni) bcol[ni] = bias[n0 + wn * 64 + ni * 16 + r16];

  if (OUTMODE != 2) {
#pragma unroll
    for (int mi = 0; mi < 4; ++mi) {
      int row = m0 + wm * 64 + mi * 16 + kg * 4;
#pragma unroll
      for (int ni = 0; ni < 4; ++ni) {
        int col = n0 + wn * 64 + ni * 16 + r16;
#pragma unroll
        for (int j = 0; j < 4; ++j) {
          float v = acc[mi][ni][j] + bcol[ni];
          _Float16 h = (_Float16)v;
          OutHi[(size_t)(row + j) * 1024 + col] = h;
          if (OUTMODE == 0)
            OutLo[(size_t)(row + j) * 1024 + col] = (_Float16)(v - (float)h);
        }
      }
    }
  } else {
    __syncthreads();
    _Float16(*T)[256] = (_Float16(*)[256])lds;
#pragma unroll
    for (int mi = 0; mi < 4; ++mi) {
      int ml = wm * 64 + mi * 16 + kg * 4;
#pragma unroll
      for (int ni = 0; ni < 4; ++ni) {
        int nl = wn * 64 + ni * 16 + r16;
#pragma unroll
        for (int j = 0; j < 4; ++j)
          T[nl][ml + j] = (_Float16)(acc[mi][ni][j] + bcol[ni]);
      }
    }
    __syncthreads();
    const int b = m0 >> 11;
    const int s0 = m0 & 2047;
#pragma unroll
    for (int r = 0; r < 8; ++r) {
      int flat = tid + r * 512;
      int n = flat >> 5, c = flat & 31;
      half8 v = *(const half8*)&T[n][c * 8];
      *(half8*)(VtOut + (size_t)b * (1024 * 2048) + (size_t)(n0 + n) * 2048 +
                s0 + c * 8) = v;
    }
  }
}

// ---------------------------------------------------------------------------
// QK^T: ring-3 counted-vmcnt, tile 64x256, 512 thr / 8 waves (validated
// round 10 engine — 92 µs, MfmaUtil 35%). Pad mask folded into the epilogue
// (same fp32 add softmax previously applied -> bit-identical logits).
// ---------------------------------------------------------------------------
__global__ __launch_bounds__(512, 4) void qk_eng(
    const _Float16* __restrict__ Qh, const _Float16* __restrict__ Ql,
    const _Float16* __restrict__ Kh, const int* __restrict__ pad,
    float* __restrict__ Lg, int bbase) {
  extern __shared__ _Float16 lds[];
  constexpr int CHUNK = 12288;  // A0 2048 | A1 2048 | B 8192 halves
  const int id = xcd_swz(blockIdx.x, gridDim.x);
  const int y = id / 144;
  int t = id % 144;
  int g4 = 0, base = 0;
  while (t >= base + (g4 + 1) * 4) { base += (g4 + 1) * 4; ++g4; }
  const int rem = t - base;
  const int qt = g4 * 4 + rem / (g4 + 1);  // 64-row q tile [0,32)
  const int kt = rem % (g4 + 1);           // 256-col k tile
  const int b = bbase + y;
  const size_t boff = (size_t)b * (2048 * 1024);
  const _Float16* A0 = Qh + boff + (size_t)(qt * 64) * 1024;
  const _Float16* A1 = Ql + boff + (size_t)(qt * 64) * 1024;
  const _Float16* B0 = Kh + boff + (size_t)(kt * 256) * 1024;
  const int tid = threadIdx.x;
  const int w = tid >> 6, lane = tid & 63;
  const int r16 = lane & 15, kg = lane >> 4;
  const int wn = w;  // 8 waves x 32 cols
  f32x4 acc[4][2];
  acc_zero42(acc);

  auto STAGE = [&](int t_, int buf) {
    _Float16* base_ = lds + buf * CHUNK;
    {
      int g = tid & 255;
      int row = g >> 2, c = g & 3;
      int cs = (c ^ (row >> 1)) & 3;
      const _Float16* src = (tid < 256) ? A0 : A1;
      _Float16* dst = base_ + ((tid < 256) ? 0 : 2048);
      gload_lds16(src + (size_t)row * 1024 + t_ * 32 + cs * 8, dst + g * 8);
    }
#pragma unroll
    for (int j = 0; j < 2; ++j) {
      int g = tid + j * 512;
      int row = g >> 2, c = g & 3;
      int cs = (c ^ (row >> 1)) & 3;
      gload_lds16(B0 + (size_t)row * 1024 + t_ * 32 + cs * 8,
                  base_ + 4096 + g * 8);
    }
  };
  auto COMPUTE = [&](int buf) {
    const _Float16* la = lds + buf * CHUNK;
    half8 a0[4], a1[4], bf[2];
#pragma unroll
    for (int mi = 0; mi < 4; ++mi) {
      int row = mi * 16 + r16;
      int off = row * 32 + SWZ(kg, row);
      a0[mi] = *(const half8*)(la + off);
      a1[mi] = *(const half8*)(la + 2048 + off);
    }
#pragma unroll
    for (int ni = 0; ni < 2; ++ni) {
      int row = wn * 32 + ni * 16 + r16;
      bf[ni] = *(const half8*)(la + 4096 + row * 32 + SWZ(kg, row));
    }
    __builtin_amdgcn_s_setprio(1);
#pragma unroll
    for (int mi = 0; mi < 4; ++mi)
#pragma unroll
      for (int ni = 0; ni < 2; ++ni) {
        acc[mi][ni] = __builtin_amdgcn_mfma_f32_16x16x32_f16(
            a0[mi], bf[ni], acc[mi][ni], 0, 0, 0);
        acc[mi][ni] = __builtin_amdgcn_mfma_f32_16x16x32_f16(
            a1[mi], bf[ni], acc[mi][ni], 0, 0, 0);
      }
    __builtin_amdgcn_s_setprio(0);
  };

  const int NS = 32;
  STAGE(0, 0);
  STAGE(1, 1);
  int tt = 0;
  for (; tt < NS - 1; ++tt) {
    asm volatile("s_waitcnt vmcnt(3)" ::: "memory");
    FENCED_BARRIER();
    if (tt + 2 < NS) STAGE(tt + 2, (tt + 2) % 3);
    COMPUTE(tt % 3);
  }
  asm volatile("s_waitcnt vmcnt(0)" ::: "memory");
  FENCED_BARRIER();
  COMPUTE(tt % 3);

  float* L = Lg + (size_t)y * (2048 * 2048);
  const int* pb = pad + (size_t)b * 2048;
#pragma unroll
  for (int ni = 0; ni < 2; ++ni) {
    int col = kt * 256 + wn * 32 + ni * 16 + r16;
    const float padd = (pb[col] == 0) ? -1.0e9f : 0.0f;
#pragma unroll
    for (int mi = 0; mi < 4; ++mi) {
      int row = qt * 64 + mi * 16 + kg * 4;
#pragma unroll
      for (int j = 0; j < 4; ++j)
        L[(size_t)(row + j) * 2048 + col] = acc[mi][ni][j] + padd;
    }
  }
}

// ---------------------------------------------------------------------------
// PV: ring-3 counted-vmcnt, tile 128x128, balanced pairing (validated r11):
// block g handles tiles g and N-1-g (work (qt+1)+(16-qt) = const 17 K-steps).
// ---------------------------------------------------------------------------
__global__ __launch_bounds__(512, 4) void pv_eng(
    const float* __restrict__ Lg, const _Float16* __restrict__ Vt,
    float* __restrict__ Out, int bbase, int ntiles) {
  extern __shared__ _Float16 lds[];
  constexpr int CHUNK = 8192;  // A 4096 | B 4096 halves
  const int g0 = xcd_swz(blockIdx.x, gridDim.x);
  const int tid = threadIdx.x;
  const int w = tid >> 6, lane = tid & 63;
  const int wm = w >> 2, wn = w & 3;
  const int r16 = lane & 15, kg = lane >> 4;

  for (int half = 0; half < 2; ++half) {
    const int idt = half ? (ntiles - 1 - g0) : g0;
    const int y = idt >> 7;
    const int qt = (idt & 127) >> 3, nt = idt & 7;
    const int b = bbase + y;
    const _Float16* P = (const _Float16*)(Lg + (size_t)y * (2048 * 2048));
    const _Float16* A0 = P + (size_t)(qt * 128) * 4096;
    const _Float16* B0 =
        Vt + (size_t)b * (1024 * 2048) + (size_t)(nt * 128) * 2048;
    const int NS = (qt + 1) * 4;
    f32x4 acc[4][2];
    acc_zero42(acc);

    auto STAGE = [&](int t_, int buf) {
      _Float16* base_ = lds + buf * CHUNK;
      int row = tid >> 2, c = tid & 3;
      int cs = (c ^ (row >> 1)) & 3;
      gload_lds16(A0 + (size_t)row * 4096 + t_ * 32 + cs * 8, base_ + tid * 8);
      gload_lds16(B0 + (size_t)row * 2048 + t_ * 32 + cs * 8,
                  base_ + 4096 + tid * 8);
    };
    auto COMPUTE = [&](int buf) {
      const _Float16* la = lds + buf * CHUNK;
      half8 a[4], bf[2];
#pragma unroll
      for (int mi = 0; mi < 4; ++mi) {
        int row = wm * 64 + mi * 16 + r16;
        a[mi] = *(const half8*)(la + row * 32 + SWZ(kg, row));
      }
#pragma unroll
      for (int ni = 0; ni < 2; ++ni) {
        int row = wn * 32 + ni * 16 + r16;
        bf[ni] = *(const half8*)(la + 4096 + row * 32 + SWZ(kg, row));
      }
      __builtin_amdgcn_s_setprio(1);
#pragma unroll
      for (int mi = 0; mi < 4; ++mi)
#pragma unroll
        for (int ni = 0; ni < 2; ++ni)
          acc[mi][ni] = __builtin_amdgcn_mfma_f32_16x16x32_f16(
              a[mi], bf[ni], acc[mi][ni], 0, 0, 0);
      __builtin_amdgcn_s_setprio(0);
    };

    STAGE(0, 0);
    STAGE(1, 1);
    int tt = 0;
    for (; tt < NS - 1; ++tt) {
      asm volatile("s_waitcnt vmcnt(2)" ::: "memory");
      FENCED_BARRIER();
      if (tt + 2 < NS) STAGE(tt + 2, (tt + 2) % 3);
      COMPUTE(tt % 3);
    }
    asm volatile("s_waitcnt vmcnt(0)" ::: "memory");
    FENCED_BARRIER();
    COMPUTE(tt % 3);

#pragma unroll
    for (int mi = 0; mi < 4; ++mi) {
      int row = qt * 128 + wm * 64 + mi * 16 + kg * 4;
#pragma unroll
      for (int ni = 0; ni < 2; ++ni) {
        int col = nt * 128 + wn * 32 + ni * 16 + r16;
#pragma unroll
        for (int j = 0; j < 4; ++j)
          Out[(size_t)(b * 2048 + row + j) * 1024 + col] = acc[mi][ni][j];
      }
    }
    if (half == 0) {
      asm volatile("s_waitcnt vmcnt(0) lgkmcnt(0)" ::: "memory");
      FENCED_BARRIER();
    }
  }
}

// ---------------------------------------------------------------------------
// Row softmax; pad mask already folded into L by qk epilogue.
// In-place fp16 P; zero-fill to 256-col boundary.
// ---------------------------------------------------------------------------
__global__ __launch_bounds__(256) void softmax_kernel(float* __restrict__ Lg,
                                                      int bbase) {
  const int q = blockIdx.x;
  const int y = blockIdx.y;
  const int tid = threadIdx.x;
  float* row = Lg + (size_t)y * (2048 * 2048) + (size_t)q * 2048;
  _Float16* prow = (_Float16*)row;
  const int kend = ((q >> 8) + 1) << 8;
  float v[8];
  int nv = 0;
  float mx = -3.0e38f;
  for (int k = tid; k <= q; k += 256) {
    float l = row[k];
    v[nv++] = l;
    mx = fmaxf(mx, l);
  }
  __shared__ float red[4];
  for (int o = 32; o; o >>= 1) mx = fmaxf(mx, __shfl_xor(mx, o));
  if ((tid & 63) == 0) red[tid >> 6] = mx;
  __syncthreads();
  mx = fmaxf(fmaxf(red[0], red[1]), fmaxf(red[2], red[3]));
  __syncthreads();
  float s = 0.f;
  for (int i = 0; i < nv; ++i) s += expf(v[i] - mx);
  for (int o = 32; o; o >>= 1) s += __shfl_xor(s, o);
  if ((tid & 63) == 0) red[tid >> 6] = s;
  __syncthreads();
  s = red[0] + red[1] + red[2] + red[3];
  const float inv = 1.0f / s;
  int i = 0;
  for (int k = tid; k <= q; k += 256) {
    prow[k] = (_Float16)(expf(v[i] - mx) * inv);
    ++i;
  }
  for (int k = q + 1 + tid; k < kend; k += 256) prow[k] = (_Float16)0.0f;
}

// ---------------------------------------------------------------------------
// Fixup for degenerate rows q < f[b] (validated rounds 4-11, verbatim).
// ---------------------------------------------------------------------------
__global__ __launch_bounds__(512) void fix_f(const int* __restrict__ pad,
                                             int* __restrict__ fb) {
  const int b = threadIdx.x >> 6, k = threadIdx.x & 63;
  unsigned long long m = __ballot(pad[b * 2048 + k] != 0);
  if (k == 0) fb[b] = m ? (__ffsll((long long)m) - 1) : 64;
}

__global__ __launch_bounds__(256) void fix_qrow2(
    const float* __restrict__ xQ, const float* __restrict__ Wq,
    const float* __restrict__ bq, const int* __restrict__ fb,
    float* __restrict__ Qrow) {
  const int b = blockIdx.y;
  const int f = fb[b];
  const int tid = threadIdx.x;
  const int e = blockIdx.x * 16 + (tid >> 4);
  const int l16 = tid & 15;
  __shared__ float xq[1024];
  for (int q = 0; q < f; ++q) {
    *(f4*)&xq[tid * 4] = ((const f4*)(xQ + (size_t)(b * 2048 + q) * 1024))[tid];
    __syncthreads();
    float a = 0.f;
#pragma unroll
    for (int it = 0; it < 16; ++it) {
      int d = l16 * 4 + it * 64;
      f4 ww = *(const f4*)(Wq + (size_t)e * 1024 + d);
      a += xq[d] * ww[0] + xq[d + 1] * ww[1] + xq[d + 2] * ww[2] +
           xq[d + 3] * ww[3];
    }
    for (int o = 8; o; o >>= 1) a += __shfl_xor(a, o);
    if (l16 == 0) Qrow[((size_t)b * 64 + q) * 1024 + e] = a + bq[e];
    __syncthreads();
  }
}

__global__ __launch_bounds__(256) void fix_qb0(const float* __restrict__ bk,
                                               const int* __restrict__ fb,
                                               const float* __restrict__ Qrow,
                                               float* __restrict__ qb0) {
  const int q = blockIdx.x, b = blockIdx.y;
  if (q >= fb[b]) return;
  const int tid = threadIdx.x;
  const float* qr = Qrow + ((size_t)b * 64 + q) * 1024;
  float p = 0.f;
  for (int e = tid; e < 1024; e += 256) p += qr[e] * bk[e];
  __shared__ float red[4];
  for (int o = 32; o; o >>= 1) p += __shfl_xor(p, o);
  if ((tid & 63) == 0) red[tid >> 6] = p;
  __syncthreads();
  if (tid == 0) qb0[b * 64 + q] = red[0] + red[1] + red[2] + red[3];
}

__global__ __launch_bounds__(256) void fix_g2(const float* __restrict__ Wk,
                                              const int* __restrict__ fb,
                                              const float* __restrict__ Qrow,
                                              float* __restrict__ Gpart) {
  const int b = blockIdx.y;
  const int f = fb[b];
  const int tid = threadIdx.x;
  const int ddblk = blockIdx.x & 3, es = blockIdx.x >> 2;
  const int dd = ddblk * 256 + tid;
  __shared__ float qc[128];
  for (int q = 0; q < f; ++q) {
    if (tid < 32)
      *(f4*)&qc[tid * 4] =
          ((const f4*)(Qrow + ((size_t)b * 64 + q) * 1024 + es * 128))[tid];
    __syncthreads();
    float g = 0.f;
    for (int e = 0; e < 128; ++e)
      g += qc[e] * Wk[(size_t)(es * 128 + e) * 1024 + dd];
    Gpart[(((size_t)es * 8 + b) * 64 + q) * 1024 + dd] = g;
    __syncthreads();
  }
}

__global__ __launch_bounds__(256) void fix_logit2(
    const float* __restrict__ xK, const int* __restrict__ pad,
    const int* __restrict__ fb, const float* __restrict__ Gpart,
    const float* __restrict__ qb0, float* __restrict__ lrow) {
  const int b = blockIdx.y;
  const int f = fb[b];
  const int tid = threadIdx.x;
  const int k = blockIdx.x * 16 + (tid >> 4);
  const int l16 = tid & 15;
  __shared__ float Gs[1024];
  for (int q = 0; q < f; ++q) {
    f4 s = (f4)0.0f;
#pragma unroll
    for (int es = 0; es < 8; ++es)
      s += ((const f4*)(Gpart + (((size_t)es * 8 + b) * 64 + q) * 1024))[tid];
    *(f4*)&Gs[tid * 4] = s;
    __syncthreads();
    float a = 0.f;
#pragma unroll
    for (int it = 0; it < 16; ++it) {
      int d = l16 * 4 + it * 64;
      f4 x = *(const f4*)(xK + (size_t)(b * 2048 + k) * 1024 + d);
      a += x[0] * Gs[d] + x[1] * Gs[d + 1] + x[2] * Gs[d + 2] +
           x[3] * Gs[d + 3];
    }
    for (int o = 8; o; o >>= 1) a += __shfl_xor(a, o);
    if (l16 == 0) {
      float l = a + qb0[b * 64 + q];
      if (pad[b * 2048 + k] == 0) l += -1.0e9f;
      if (k > q) l += -1.0e9f;
      lrow[((size_t)b * 64 + q) * 2048 + k] = l;
    }
    __syncthreads();
  }
}

__global__ __launch_bounds__(256) void fix_sm(const int* __restrict__ fb,
                                              float* __restrict__ lrow,
                                              float* __restrict__ srow) {
  const int q = blockIdx.x, b = blockIdx.y;
  if (q >= fb[b]) return;
  const int tid = threadIdx.x;
  float* row = lrow + ((size_t)b * 64 + q) * 2048;
  float v[8];
  float mx = -3.0e38f;
#pragma unroll
  for (int i = 0; i < 8; ++i) {
    v[i] = row[tid + i * 256];
    mx = fmaxf(mx, v[i]);
  }
  __shared__ float red[4];
  for (int o = 32; o; o >>= 1) mx = fmaxf(mx, __shfl_xor(mx, o));
  if ((tid & 63) == 0) red[tid >> 6] = mx;
  __syncthreads();
  mx = fmaxf(fmaxf(red[0], red[1]), fmaxf(red[2], red[3]));
  __syncthreads();
  float s = 0.f;
#pragma unroll
  for (int i = 0; i < 8; ++i) {
    v[i] = expf(v[i] - mx);
    s += v[i];
  }
#pragma unroll
  for (int i = 0; i < 8; ++i) row[tid + i * 256] = v[i];
  for (int o = 32; o; o >>= 1) s += __shfl_xor(s, o);
  if ((tid & 63) == 0) red[tid >> 6] = s;
  __syncthreads();
  if (tid == 0) srow[b * 64 + q] = red[0] + red[1] + red[2] + red[3];
}

__global__ __launch_bounds__(256) void fix_pv2(
    const _Float16* __restrict__ Vt, const int* __restrict__ fb,
    const float* __restrict__ lrow, const float* __restrict__ srow,
    float* __restrict__ Out) {
  const int b = blockIdx.y;
  const int f = fb[b];
  const int tid = threadIdx.x;
  const int d = blockIdx.x * 16 + (tid >> 4);
  const int l16 = tid & 15;
  __shared__ float ps[2048];
  for (int q = 0; q < f; ++q) {
    const f4* src = (const f4*)(lrow + ((size_t)b * 64 + q) * 2048);
    *(f4*)&ps[tid * 8] = src[tid * 2];
    *(f4*)&ps[tid * 8 + 4] = src[tid * 2 + 1];
    __syncthreads();
    float o = 0.f;
#pragma unroll
    for (int it = 0; it < 16; ++it) {
      int k = l16 * 8 + it * 128;
      half8 vv = *(const half8*)(Vt + (size_t)b * (1024 * 2048) +
                                 (size_t)d * 2048 + k);
      o += (float)vv[0] * ps[k] + (float)vv[1] * ps[k + 1] +
           (float)vv[2] * ps[k + 2] + (float)vv[3] * ps[k + 3] +
           (float)vv[4] * ps[k + 4] + (float)vv[5] * ps[k + 5] +
           (float)vv[6] * ps[k + 6] + (float)vv[7] * ps[k + 7];
    }
    for (int of = 8; of; of >>= 1) o += __shfl_xor(o, of);
    if (l16 == 0)
      Out[(size_t)(b * 2048 + q) * 1024 + d] = o * (1.0f / srow[b * 64 + q]);
    __syncthreads();
  }
}

// ---------------------------------------------------------------------------
extern "C" void kernel_launch(void* const* d_in, const int* in_sizes, int n_in,
                              void* d_out, int out_size, void* d_ws,
                              size_t ws_size, hipStream_t stream) {
  const float* xQ = (const float*)d_in[0];
  const float* xK = (const float*)d_in[1];
  const float* xV = (const float*)d_in[2];
  const int* pad = (const int*)d_in[3];
  const float* Wq = (const float*)d_in[5];
  const float* bq = (const float*)d_in[6];
  const float* Wk = (const float*)d_in[7];
  const float* bk = (const float*)d_in[8];
  const float* Wv = (const float*)d_in[9];
  const float* bv = (const float*)d_in[10];
  float* Out = (float*)d_out;

  const size_t MB = (size_t)1 << 20;
  char* wsb = (char*)d_ws;
  // Persistent: Qh [0,32) Ql [32,64) Kh [64,96) Vt [96,128); Lg at 128.
  _Float16* Qh = (_Float16*)(wsb);
  _Float16* Ql = (_Float16*)(wsb + 32 * MB);
  _Float16* Kh = (_Float16*)(wsb + 64 * MB);
  _Float16* Vt = (_Float16*)(wsb + 96 * MB);
  float* Lg = (float*)(wsb + 128 * MB);

  size_t avail = (ws_size > 128 * MB) ? ws_size - 128 * MB : 0;
  int G = (int)(avail / (16 * MB));
  if (G > 8) G = 8;
  if (G < 1) G = 1;

  const int SM_P1 = 73728;  // proj3 WSPLIT=1: 3 x 24KB
  const int SM_P0 = 49152;  // proj3 WSPLIT=0: 3 x 16KB
  const int SM_F = 65536;   // proj_fused fallback
  const int SM_QK = 73728;  // 3 x 24KB
  const int SM_PV = 49152;  // 3 x 16KB
  (void)hipFuncSetAttribute((const void*)&proj3<1, 0>,
                            hipFuncAttributeMaxDynamicSharedMemorySize, SM_P1);
  (void)hipFuncSetAttribute((const void*)&proj3<1, 1>,
                            hipFuncAttributeMaxDynamicSharedMemorySize, SM_P1);
  (void)hipFuncSetAttribute((const void*)&proj3<0, 2>,
                            hipFuncAttributeMaxDynamicSharedMemorySize, SM_P0);
  (void)hipFuncSetAttribute((const void*)&proj_fused<1, 0>,
                            hipFuncAttributeMaxDynamicSharedMemorySize, SM_F);
  (void)hipFuncSetAttribute((const void*)&proj_fused<1, 1>,
                            hipFuncAttributeMaxDynamicSharedMemorySize, SM_F);
  (void)hipFuncSetAttribute((const void*)&proj_fused<0, 2>,
                            hipFuncAttributeMaxDynamicSharedMemorySize, SM_F);
  (void)hipFuncSetAttribute((const void*)&qk_eng,
                            hipFuncAttributeMaxDynamicSharedMemorySize, SM_QK);
  (void)hipFuncSetAttribute((const void*)&pv_eng,
                            hipFuncAttributeMaxDynamicSharedMemorySize, SM_PV);

  dim3 blk(256), eblk(512);

  if (ws_size >= 165 * MB) {
    // Fast path (validated round 10): pre-convert X + ring-3 proj3.
    {
      _Float16* sX = (_Float16*)(wsb);
      _Float16* sW = (_Float16*)(wsb + 32 * MB);
      cvt_plain<<<dim3(2048), blk, 0, stream>>>(xV, sX, 4194304);
      cvt_plain<<<dim3(1024), blk, 0, stream>>>(Wv, sW, 262144);
      proj3<0, 2><<<dim3(1024), eblk, SM_P0, stream>>>(sX, sW, sW, bv, nullptr,
                                                       nullptr, Vt);
    }
    {
      _Float16* sX = (_Float16*)(wsb);
      _Float16* sWh = (_Float16*)(wsb + 32 * MB);
      _Float16* sWl = (_Float16*)(wsb + 34 * MB);
      cvt_plain<<<dim3(2048), blk, 0, stream>>>(xK, sX, 4194304);
      cvt_split<<<dim3(1024), blk, 0, stream>>>(Wk, sWh, sWl, 262144);
      proj3<1, 1><<<dim3(1024), eblk, SM_P1, stream>>>(sX, sWh, sWl, bk, Kh,
                                                       nullptr, nullptr);
    }
    {
      _Float16* sX = (_Float16*)(wsb + 128 * MB);
      _Float16* sWh = (_Float16*)(wsb + 160 * MB);
      _Float16* sWl = (_Float16*)(wsb + 162 * MB);
      cvt_plain<<<dim3(2048), blk, 0, stream>>>(xQ, sX, 4194304);
      cvt_split<<<dim3(1024), blk, 0, stream>>>(Wq, sWh, sWl, 262144);
      proj3<1, 0><<<dim3(1024), eblk, SM_P1, stream>>>(sX, sWh, sWl, bq, Qh,
                                                       Ql, nullptr);
    }
  } else {
    _Float16* Wqh = (_Float16*)(wsb + 128 * MB);
    _Float16* Wql = (_Float16*)(wsb + 130 * MB);
    _Float16* Wkh = (_Float16*)(wsb + 132 * MB);
    _Float16* Wkl = (_Float16*)(wsb + 134 * MB);
    _Float16* Wvh = (_Float16*)(wsb + 136 * MB);
    cvt_split<<<dim3(1024), blk, 0, stream>>>(Wq, Wqh, Wql, 262144);
    cvt_split<<<dim3(1024), blk, 0, stream>>>(Wk, Wkh, Wkl, 262144);
    cvt_plain<<<dim3(1024), blk, 0, stream>>>(Wv, Wvh, 262144);
    proj_fused<0, 2><<<dim3(512), eblk, SM_F, stream>>>(xV, Wvh, Wvh, bv,
                                                        nullptr, nullptr, Vt);
    proj_fused<1, 1><<<dim3(512), eblk, SM_F, stream>>>(xK, Wkh, Wkl, bk, Kh,
                                                        nullptr, nullptr);
    proj_fused<1, 0><<<dim3(512), eblk, SM_F, stream>>>(xQ, Wqh, Wql, bq, Qh,
                                                        Ql, nullptr);
  }

  // --- Attention ---
  for (int bbase = 0; bbase < 8; bbase += G) {
    int nb = (8 - bbase < G) ? (8 - bbase) : G;
    qk_eng<<<dim3(144 * nb), eblk, SM_QK, stream>>>(Qh, Ql, Kh, pad, Lg,
                                                    bbase);
    softmax_kernel<<<dim3(2048, nb), blk, 0, stream>>>(Lg, bbase);
    pv_eng<<<dim3(64 * nb), eblk, SM_PV, stream>>>(Lg, Vt, Out, bbase,
                                                   128 * nb);
  }

  // --- Fixup: scratch in [0,24) MB (Qh dead after last qk) ---
  int* fb = (int*)(wsb);
  float* qb0 = (float*)(wsb + 4 * 1024);
  float* srow = (float*)(wsb + 8 * 1024);
  float* Qrow = (float*)(wsb + 1 * MB);   // 2 MB
  float* Gpart = (float*)(wsb + 4 * MB);  // 16 MB
  float* lrow = (float*)(wsb + 20 * MB);  // 4 MB

  fix_f<<<dim3(1), dim3(512), 0, stream>>>(pad, fb);
  fix_qrow2<<<dim3(64, 8), blk, 0, stream>>>(xQ, Wq, bq, fb, Qrow);
  fix_qb0<<<dim3(64, 8), blk, 0, stream>>>(bk, fb, Qrow, qb0);
  fix_g2<<<dim3(32, 8), blk, 0, stream>>>(Wk, fb, Qrow, Gpart);
  fix_logit2<<<dim3(128, 8), blk, 0, stream>>>(xK, pad, fb, Gpart, qb0, lrow);
  fix_sm<<<dim3(64, 8), blk, 0, stream>>>(fb, lrow, srow);
  fix_pv2<<<dim3(64, 8), blk, 0, stream>>>(Vt, fb, lrow, srow, Out);
}